// Round 13
// baseline (534.261 us; speedup 1.0000x reference)
//
#include <hip/hip_runtime.h>
#include <math.h>

#define TMASK 524287   // 2^19 - 1
#define PM0 455773     // 73856093 % 2^19
#define PM1 475295     // 19349663 % 2^19
#define PM2 130999     // 83492791 % 2^19

typedef __attribute__((ext_vector_type(8))) short bf16x8;
typedef __attribute__((ext_vector_type(4))) float f32x4;

// Transposed-bf16 weight buffer layout in d_ws (element offsets, shorts):
#define OFF_W0   0       // [128][64]   (K=52  pad 64)
#define OFF_W1   8192    // [128][128]
#define OFF_W2   24576   // [128][192]  (K=180 pad 192)
#define OFF_W3   49152   // [128][128]
#define OFF_E    65536   // [64][128]   E,M contiguous (8 tiles)
#define OFF_P    81920   // [32][128]
#define OFF_MAT  86016   // [64][128]   MAT,S contiguous (8 tiles)
#define OFF_S    94208   // [64][128]
#define OFF_BD   102400  // [32][288] block-diagonal fused head-l2 matrix, k-order E|M|MAT|S|P
#define WT_TOTAL 102400
#define WT_ALLOC 111616  // + BD region

// ws byte layout: wt | tab8 int8[16][524288][2] (16 MiB) | feat uint[8][N] | dense
#define WS_TAB8_OFF (WT_ALLOC*2)
#define TAB8_BYTES  (16u*524288u*2u)
#define WS_FEAT_OFF (WS_TAB8_OFF + TAB8_BYTES)
// dense tables levels 0-7 (res 16/20/25/32/40/50/64/80), ushort entries.
// ushort offs {0,4096,12096,27728,60496,124496,249496,511640}, total 1023640
#define DENSE_USHORTS 1023640
#define DENSE_BYTES   (DENSE_USHORTS*2)

#define TAB_SCALE   131072.0f
#define TAB_INV     (1.0f/131072.0f)

// ---- MLP LDS layout: ONE shared arena (N-split: both waves, same 32 pts)
#define A6_H    0        // bf16[32][136]
#define A6_HL   8704     // bf16[32][136]
#define A6_FB   8704     // bf16[32][72] aliases HL (dead before HL written)
                         // R2 f32[32][20] aliases too (written after BD3)
#define LDS6_TOTAL 17408

struct Params {
  const float* x; const float* freq; const float* tables;
  const float* b0; const float* b1; const float* b2; const float* b3;
  const float* e_b1; const float* e_w2; const float* e_b2; const float* e_g; const float* e_be;
  const float* m_b1; const float* m_w2; const float* m_b2; const float* m_g; const float* m_be;
  const float* p_b1; const float* p_w2; const float* p_b2;
  const float* mat_b1; const float* mat_w2; const float* mat_b2;
  const float* s_b1; const float* s_w2; const float* s_b2;
  const short* wt;
  const unsigned* feat;        // [8][N] level-major (levels 8..15)
  const unsigned short* dense; // levels 0..7 direct-indexed
  float* out;
  int N;
  int res[16];
};

struct HashParams {
  const float* x; const unsigned short* tab8; unsigned* feat; int N; int res[16];
};
struct DensePrepParams { const unsigned short* tab8; unsigned short* dense; };
struct TabPrepParams { const float* tables; unsigned* tab8; };
struct PrepParams {
  const float* src[9];
  int end[9]; int Nsrc[9]; int Ksrc[9]; int Kpad[9];
  short* wt;
};
struct BdParams {
  const float* e; const float* m; const float* p; const float* mat; const float* s;
  short* out;
};

__device__ __forceinline__ short f2bf(float f){
  union { float f; unsigned u; } v; v.f = f;
  unsigned r = v.u + 0x7fffu + ((v.u >> 16) & 1u);   // RNE
  return (short)(r >> 16);
}
__device__ __forceinline__ float bf2f(short s){
  union { unsigned u; float f; } v; v.u = ((unsigned)(unsigned short)s) << 16; return v.f;
}
__device__ __forceinline__ float sigmoid_(float v){ return 1.f/(1.f + expf(-v)); }

// ---------------- weight transpose+bf16 prep
__global__ __launch_bounds__(256)
void prep_weights(PrepParams P)
{
  int id = blockIdx.x*256 + threadIdx.x;
  if (id >= WT_TOTAL) return;
  int r = 0, base = 0;
  #pragma unroll
  for (int i = 0; i < 9; ++i) { if (id >= P.end[i]) { r = i+1; base = P.end[i]; } }
  const int rel = id - base;
  const int kp = P.Kpad[r];
  const int n = rel / kp;
  const int k = rel - n*kp;
  float v = 0.f;
  if (k < P.Ksrc[r]) v = P.src[r][k * P.Nsrc[r] + n];
  P.wt[id] = f2bf(v);
}

// ---------------- block-diagonal fused head-l2 matrix [32 n][288 k]
// k-order: E 0..63 | M 64..127 | MAT 128..191 | S 192..255 | P 256..287
__global__ __launch_bounds__(256)
void prep_bd(BdParams P)
{
  int id = blockIdx.x*256 + threadIdx.x;
  if (id >= 32*288) return;
  const int n = id / 288, k = id - n*288;
  float v = 0.f;
  if      (n < 3  && k < 64)                        v = P.e[k*3 + n];
  else if (n >= 3 && n < 6  && k >= 64  && k < 128) v = P.m[(k-64)*3 + (n-3)];
  else if (n >= 6 && n < 12 && k >= 256)            v = P.p[(k-256)*6 + (n-6)];
  else if (n >= 12&& n < 15 && k >= 128 && k < 192) v = P.mat[(k-128)*3 + (n-12)];
  else if (n >= 15&& n < 19 && k >= 192 && k < 256) v = P.s[(k-192)*4 + (n-15)];
  P.out[id] = f2bf(v);
}

// ---------------- table quantize fp32 -> int8 (scale 2^17)
__global__ __launch_bounds__(256)
void tab_prep(TabPrepParams P)
{
  const unsigned id = blockIdx.x*256 + threadIdx.x;
  if (id >= 16u*524288u/2u) return;
  const float4 v = ((const float4*)P.tables)[id];
  int q0 = (int)fminf(fmaxf(rintf(v.x*TAB_SCALE), -127.f), 127.f);
  int q1 = (int)fminf(fmaxf(rintf(v.y*TAB_SCALE), -127.f), 127.f);
  int q2 = (int)fminf(fmaxf(rintf(v.z*TAB_SCALE), -127.f), 127.f);
  int q3 = (int)fminf(fmaxf(rintf(v.w*TAB_SCALE), -127.f), 127.f);
  unsigned pack = (q0 & 255) | ((q1 & 255) << 8) | ((q2 & 255) << 16) | ((q3 & 255) << 24);
  P.tab8[id] = pack;
}

// ---------------- densify levels 0-7 (res 16..80) from tab8
// dense[l][(cx*res+cy)*res+cz] = tab8[l][hash(cx,cy,cz)] -- identical values.
__global__ __launch_bounds__(256)
void dense_prep8(DensePrepParams P)
{
  const int id = blockIdx.x*256 + threadIdx.x;
  if (id >= DENSE_USHORTS) return;
  int l = 0, base = 0, res = 16;
  if (id >= 4096)   { l = 1; base = 4096;   res = 20; }
  if (id >= 12096)  { l = 2; base = 12096;  res = 25; }
  if (id >= 27728)  { l = 3; base = 27728;  res = 32; }
  if (id >= 60496)  { l = 4; base = 60496;  res = 40; }
  if (id >= 124496) { l = 5; base = 124496; res = 50; }
  if (id >= 249496) { l = 6; base = 249496; res = 64; }
  if (id >= 511640) { l = 7; base = 511640; res = 80; }
  const int c = id - base;
  if (c >= res*res*res) return;   // pad gap (level 2)
  const int cz = c % res;
  const int t  = c / res;
  const int cy = t % res;
  const int cx = t / res;
  const unsigned h = (unsigned)((cx*PM0 + cy*PM1 + cz*PM2) & TMASK);
  P.dense[id] = P.tab8[((unsigned)l << 19) + h];
}

// ---------------- per-XCD fine hash, levels 8..15, 2 pts/thread.
// 8 units = 8 levels; unit = b%8 -> XCD = b%8 = level: each XCD owns ONE 1MB
// level table (fully L2-resident) and all N points for it. Table gathers use
// nontemporal loads (random 2B reads, ~2% L1 hit -> skip L1 allocation).
__global__ __launch_bounds__(256, 8)
void hash_encode8u(HashParams P)
{
  const int b = blockIdx.x;
  const int l = 8 + (b & 7);
  const int strip = b >> 3;
  const int pA = strip*512 + threadIdx.x;
  if (pA >= P.N) return;
  const int pB0 = pA + 256;
  const bool sB = pB0 < P.N;
  const int pB = sB ? pB0 : pA;

  const int res = P.res[l];
  const float rf = (float)(res-1);
  const unsigned short* tp = P.tab8 + ((size_t)l << 19);

  const float xA0 = fminf(fmaxf(P.x[pA*3+0], 0.f), 1.f);
  const float xA1 = fminf(fmaxf(P.x[pA*3+1], 0.f), 1.f);
  const float xA2 = fminf(fmaxf(P.x[pA*3+2], 0.f), 1.f);
  const float sA0 = xA0*rf, sA1 = xA1*rf, sA2 = xA2*rf;
  int fA0 = (int)sA0; if (fA0 > res-1) fA0 = res-1;
  int fA1 = (int)sA1; if (fA1 > res-1) fA1 = res-1;
  int fA2 = (int)sA2; if (fA2 > res-1) fA2 = res-1;
  const float wA0 = sA0 - (float)fA0;
  const float wA1 = sA1 - (float)fA1;
  const float wA2 = sA2 - (float)fA2;
  int cA0 = fA0+1; if (cA0 > res-1) cA0 = res-1;
  int cA1 = fA1+1; if (cA1 > res-1) cA1 = res-1;
  int cA2 = fA2+1; if (cA2 > res-1) cA2 = res-1;
  const int hxA0 = (fA0*PM0) & TMASK, hxA1 = (cA0*PM0) & TMASK;
  const int hyA0 = (fA1*PM1) & TMASK, hyA1 = (cA1*PM1) & TMASK;
  const int hzA0 = (fA2*PM2) & TMASK, hzA1 = (cA2*PM2) & TMASK;

  const float xB0 = fminf(fmaxf(P.x[pB*3+0], 0.f), 1.f);
  const float xB1 = fminf(fmaxf(P.x[pB*3+1], 0.f), 1.f);
  const float xB2 = fminf(fmaxf(P.x[pB*3+2], 0.f), 1.f);
  const float sB0 = xB0*rf, sB1 = xB1*rf, sB2 = xB2*rf;
  int fB0 = (int)sB0; if (fB0 > res-1) fB0 = res-1;
  int fB1 = (int)sB1; if (fB1 > res-1) fB1 = res-1;
  int fB2 = (int)sB2; if (fB2 > res-1) fB2 = res-1;
  const float wB0 = sB0 - (float)fB0;
  const float wB1 = sB1 - (float)fB1;
  const float wB2 = sB2 - (float)fB2;
  int cB0 = fB0+1; if (cB0 > res-1) cB0 = res-1;
  int cB1 = fB1+1; if (cB1 > res-1) cB1 = res-1;
  int cB2 = fB2+1; if (cB2 > res-1) cB2 = res-1;
  const int hxB0 = (fB0*PM0) & TMASK, hxB1 = (cB0*PM0) & TMASK;
  const int hyB0 = (fB1*PM1) & TMASK, hyB1 = (cB1*PM1) & TMASK;
  const int hzB0 = (fB2*PM2) & TMASK, hzB1 = (cB2*PM2) & TMASK;

  // 16 gathers in flight; nontemporal (bypass L1 allocation)
  unsigned short tvA[8], tvB[8];
  #pragma unroll
  for (int cn = 0; cn < 8; ++cn) {
    const int bx = (cn>>2)&1, by = (cn>>1)&1, bz = cn&1;
    tvA[cn] = __builtin_nontemporal_load(
        tp + (((bx?hxA1:hxA0) + (by?hyA1:hyA0) + (bz?hzA1:hzA0)) & TMASK));
    tvB[cn] = __builtin_nontemporal_load(
        tp + (((bx?hxB1:hxB0) + (by?hyB1:hyB0) + (bz?hzB1:hzB0)) & TMASK));
  }

  unsigned* fl = P.feat + (size_t)(l-8)*P.N;
  {
    float a0 = 0.f, a1 = 0.f;
    #pragma unroll
    for (int cn = 0; cn < 8; ++cn) {
      const int bx = (cn>>2)&1, by = (cn>>1)&1, bz = cn&1;
      const float cw = (bx?wA0:1.f-wA0)*(by?wA1:1.f-wA1)*(bz?wA2:1.f-wA2);
      a0 = fmaf(cw, (float)(int)(signed char)(tvA[cn] & 0xff), a0);
      a1 = fmaf(cw, (float)(int)(signed char)(tvA[cn] >> 8),   a1);
    }
    a0 *= TAB_INV; a1 *= TAB_INV;
    fl[pA] = (unsigned)(unsigned short)f2bf(a0)
           | ((unsigned)(unsigned short)f2bf(a1) << 16);
  }
  if (sB) {
    float a0 = 0.f, a1 = 0.f;
    #pragma unroll
    for (int cn = 0; cn < 8; ++cn) {
      const int bx = (cn>>2)&1, by = (cn>>1)&1, bz = cn&1;
      const float cw = (bx?wB0:1.f-wB0)*(by?wB1:1.f-wB1)*(bz?wB2:1.f-wB2);
      a0 = fmaf(cw, (float)(int)(signed char)(tvB[cn] & 0xff), a0);
      a1 = fmaf(cw, (float)(int)(signed char)(tvB[cn] >> 8),   a1);
    }
    a0 *= TAB_INV; a1 *= TAB_INV;
    fl[pB] = (unsigned)(unsigned short)f2bf(a0)
           | ((unsigned)(unsigned short)f2bf(a1) << 16);
  }
}

// ---------------- dense trilinear blend helper (direct-indexed table)
__device__ __forceinline__ unsigned dense_blend(
    const unsigned short* __restrict__ dp, int res,
    float xs0, float xs1, float xs2)
{
  const float rf = (float)(res-1);
  const float s0 = xs0*rf, s1 = xs1*rf, s2 = xs2*rf;
  int f0i = (int)s0; if (f0i > res-1) f0i = res-1;
  int f1i = (int)s1; if (f1i > res-1) f1i = res-1;
  int f2i = (int)s2; if (f2i > res-1) f2i = res-1;
  const float w0 = s0 - (float)f0i;
  const float w1 = s1 - (float)f1i;
  const float w2 = s2 - (float)f2i;
  int c0i = f0i+1; if (c0i > res-1) c0i = res-1;
  int c1i = f1i+1; if (c1i > res-1) c1i = res-1;
  int c2i = f2i+1; if (c2i > res-1) c2i = res-1;
  const int sx0 = f0i*res*res, sx1 = c0i*res*res;
  const int ty0 = f1i*res,     ty1 = c1i*res;
  unsigned short tv[8];
  #pragma unroll
  for (int cn = 0; cn < 8; ++cn) {
    const int bx = (cn>>2)&1, by = (cn>>1)&1, bz = cn&1;
    tv[cn] = dp[(bx?sx1:sx0) + (by?ty1:ty0) + (bz?c2i:f2i)];
  }
  float a0 = 0.f, a1 = 0.f;
  #pragma unroll
  for (int cn = 0; cn < 8; ++cn) {
    const int bx = (cn>>2)&1, by = (cn>>1)&1, bz = cn&1;
    const float cw = (bx?w0:1.f-w0)*(by?w1:1.f-w1)*(bz?w2:1.f-w2);
    a0 = fmaf(cw, (float)(int)(signed char)(tv[cn] & 0xff), a0);
    a1 = fmaf(cw, (float)(int)(signed char)(tv[cn] >> 8),   a1);
  }
  a0 *= TAB_INV; a1 *= TAB_INV;
  return (unsigned)(unsigned short)f2bf(a0)
       | ((unsigned)(unsigned short)f2bf(a1) << 16);
}

// ---------------- M=32 MFMA phase with depth-1 B prefetch (ping-pong regs)
template<int NT, int KC>
__device__ __forceinline__ void gemm32(f32x4* acc0, f32x4* acc1,
    const short* A, int lda, const short* __restrict__ wt, int kpad, int kwoff,
    int n0, int q)
{
  const short* Ap0 = A + n0*lda + q*8;
  const short* Ap1 = Ap0 + 16*lda;
  const short* Bp  = wt + n0*kpad + kwoff + q*8;
  bf16x8 bc[NT], bn[NT];
  #pragma unroll
  for (int nt = 0; nt < NT; ++nt) bc[nt] = *(const bf16x8*)(Bp + nt*16*kpad);
  #pragma unroll
  for (int kc = 0; kc < KC; ++kc) {
    if (kc + 1 < KC) {
      #pragma unroll
      for (int nt = 0; nt < NT; ++nt)
        bn[nt] = *(const bf16x8*)(Bp + nt*16*kpad + (kc+1)*32);
    }
    const bf16x8 a0 = *(const bf16x8*)(Ap0 + kc*32);
    const bf16x8 a1 = *(const bf16x8*)(Ap1 + kc*32);
    #pragma unroll
    for (int nt = 0; nt < NT; ++nt) {
      acc0[nt] = __builtin_amdgcn_mfma_f32_16x16x32_bf16(a0, bc[nt], acc0[nt], 0, 0, 0);
      acc1[nt] = __builtin_amdgcn_mfma_f32_16x16x32_bf16(a1, bc[nt], acc1[nt], 0, 0, 0);
    }
    #pragma unroll
    for (int nt = 0; nt < NT; ++nt) bc[nt] = bn[nt];
  }
}

// trunk epilogue: bias(reg) + relu + f2bf -> LDS (C: col=lane&15, row=(lane>>4)*4+reg)
template<int NT>
__device__ __forceinline__ void epi_trunk(const f32x4* acc0, const f32x4* acc1,
    const float* bv4, short* out, int ldo, int n0, int q, int coff)
{
  #pragma unroll
  for (int nt = 0; nt < NT; ++nt) {
    const float bv = bv4[nt];
    #pragma unroll
    for (int r = 0; r < 4; ++r) {
      float v0 = fmaxf(acc0[nt][r] + bv, 0.f);
      float v1 = fmaxf(acc1[nt][r] + bv, 0.f);
      out[(q*4 + r)*ldo + coff + nt*16 + n0]      = f2bf(v0);
      out[(16 + q*4 + r)*ldo + coff + nt*16 + n0] = f2bf(v1);
    }
  }
}

// N-split kernel: 2 waves share one 32-point arena; wave w owns output cols
// w*64..w*64+63 of every trunk layer (and its half of the heads).
// Levels 0-7 inline from dense tables; levels 8-15 from feat[8][N].
// Register-pressure discipline (R10/R11 spill lesson): per-lane constants are
// loaded AFTER the staging barrier so they don't coexist with blend temps;
// each blend pack is stored to LDS immediately after computation.
__global__ __launch_bounds__(128, 4)
void em_nerf6(Params P)
{
  __shared__ __align__(16) char smem[LDS6_TOTAL];
  const int tid = threadIdx.x;
  const int lane = tid & 63, wave = tid >> 6;
  short* H  = (short*)(smem + A6_H);
  short* HL = (short*)(smem + A6_HL);
  short* FB = (short*)(smem + A6_FB);
  float* R2 = (float*)(smem + A6_HL);
  const int n0 = lane & 15, q = lane >> 4;
  const int p0 = blockIdx.x*32;
  const int ntb = wave*64;   // this wave's output-column base (4 tiles)

  // thread roles for staging: point pp = tid&31, group lg = tid>>5 (0..3)
  const int pp = tid & 31;
  const int lg = tid >> 5;
  int gp = p0 + pp; if (gp >= P.N) gp = P.N - 1;

  // hash-feat loads issued first: feat [8][N]; thread loads levels lg*2, lg*2+1
  unsigned fw2[2];
  #pragma unroll
  for (int j = 0; j < 2; ++j)
    fw2[j] = P.feat[(size_t)(lg*2 + j)*P.N + gp];

  // point coords (shared by coarse + mid dense blends)
  const float xs0 = fminf(fmaxf(P.x[gp*3+0], 0.f), 1.f);
  const float xs1 = fminf(fmaxf(P.x[gp*3+1], 0.f), 1.f);
  const float xs2 = fminf(fmaxf(P.x[gp*3+2], 0.f), 1.f);

  // coarse level lg (0..3) inline from dense -> LDS immediately
  {
    const int lo  = (lg & 1) ? 20 : 16;
    const int hi  = (lg & 1) ? 32 : 25;
    const int res = (lg & 2) ? hi : lo;
    const unsigned dlo  = (lg & 1) ? 4096u  : 0u;
    const unsigned dhi  = (lg & 1) ? 27728u : 12096u;
    const unsigned doff = (lg & 2) ? dhi : dlo;
    *(unsigned*)&FB[pp*72 + 2*lg] = dense_blend(P.dense + doff, res, xs0, xs1, xs2);
  }

  // mid level 4+lg inline from dense (L2-resident ~2MB) -> LDS immediately
  {
    const int lo  = (lg & 1) ? 50 : 40;
    const int hi  = (lg & 1) ? 80 : 64;
    const int res = (lg & 2) ? hi : lo;
    const unsigned dlo  = (lg & 1) ? 124496u : 60496u;
    const unsigned dhi  = (lg & 1) ? 511640u : 249496u;
    const unsigned doff = (lg & 2) ? dhi : dlo;
    *(unsigned*)&FB[pp*72 + 8 + 2*lg] = dense_blend(P.dense + doff, res, xs0, xs1, xs2);
  }

  // freq encode: 4 threads per point, bands i = lg, lg+4, ...
  {
    float fr = P.freq[gp];
    fr = fminf(fmaxf(fr, 1e6f), 1e12f);
    const float nf = (log10f(fr) - 6.f) * (1.f/6.f);
    const float a0 = 3.14159274101257324f * nf;
    #pragma clang loop unroll(disable)
    for (int i = lg; i < 10; i += 4) {
      const float a = a0 * (float)(1 << i);   // exact pow2 scale == iterative doubling
      FB[pp*72 + 32 + 2*i] = f2bf(sinf(a));
      FB[pp*72 + 33 + 2*i] = f2bf(cosf(a));
    }
    if (lg == 3) {
      #pragma unroll
      for (int k = 52; k < 64; ++k) FB[pp*72 + k] = 0;
    }
  }

  // hash-feat store: levels 8+lg*2+j -> FB shorts [16+2*(lg*2+j) ...]
  #pragma unroll
  for (int j = 0; j < 2; ++j)
    *(unsigned*)&FB[pp*72 + 16 + 4*lg + 2*j] = fw2[j];
  __syncthreads();

  // per-lane constants -> VGPRs AFTER the barrier (loads overlap W0 gemm;
  // keeps staging-phase register pressure low -> no scratch spill)
  float rb0[4], rb1[4], rb2[4], rb3[4], rbem[4], rbms[4], rg[4], rbe[4];
  {
    const float* embp = wave ? P.m_b1 : P.e_b1;
    const float* msbp = wave ? P.s_b1 : P.mat_b1;
    const float* ggp  = wave ? P.m_g  : P.e_g;
    const float* bbep = wave ? P.m_be : P.e_be;
    #pragma unroll
    for (int nt = 0; nt < 4; ++nt) {
      const int c  = ntb + nt*16 + n0;
      const int ch = nt*16 + n0;
      rb0[nt] = P.b0[c]; rb1[nt] = P.b1[c]; rb2[nt] = P.b2[c]; rb3[nt] = P.b3[c];
      rbem[nt] = embp[ch]; rbms[nt] = msbp[ch];
      rg[nt] = ggp[ch]; rbe[nt] = bbep[ch];
    }
  }
  const float rpb = P.p_b1[wave*16 + n0];
  float rc;
  if (wave == 0) {
    if      (n0 < 3)  rc = P.e_b2[n0];
    else if (n0 < 6)  rc = P.m_b2[n0-3];
    else if (n0 < 12) rc = P.p_b2[n0-6];
    else if (n0 < 15) rc = P.mat_b2[n0-12];
    else              rc = P.s_b2[0];
  } else {
    rc = (n0 < 3) ? P.s_b2[1 + n0] : 0.f;
  }

  // ---- trunk (each layer: gemm reads, barrier, epi writes, barrier)
  { f32x4 a0[4] = {}, a1[4] = {};
    gemm32<4,2>(a0, a1, FB, 72, P.wt + OFF_W0 + ntb*64, 64, 0, n0, q);
    // W0 writes H (first write) while other wave may still read FB: disjoint.
    epi_trunk<4>(a0, a1, rb0, H, 136, n0, q, ntb);
    __syncthreads(); }
  { f32x4 a0[4] = {}, a1[4] = {};
    gemm32<4,4>(a0, a1, H, 136, P.wt + OFF_W1 + ntb*128, 128, 0, n0, q);
    __syncthreads();
    epi_trunk<4>(a0, a1, rb1, H, 136, n0, q, ntb);
    __syncthreads(); }
  { f32x4 a0[4] = {}, a1[4] = {};
    gemm32<4,4>(a0, a1, H, 136, P.wt + OFF_W2 + ntb*192, 192, 0, n0, q);
    gemm32<4,2>(a0, a1, FB, 72, P.wt + OFF_W2 + ntb*192, 192, 128, n0, q);
    __syncthreads();
    epi_trunk<4>(a0, a1, rb2, H, 136, n0, q, ntb);
    __syncthreads(); }
  { f32x4 a0[4] = {}, a1[4] = {};
    gemm32<4,4>(a0, a1, H, 136, P.wt + OFF_W3 + ntb*128, 128, 0, n0, q);
    __syncthreads();
    epi_trunk<4>(a0, a1, rb3, H, 136, n0, q, ntb);
    __syncthreads(); }
  // FB dead from here; HL (aliasing FB region) becomes live.

  // ---- head l1 phase A: wave0 = E (4 tiles + LN), wave1 = M (4 tiles + LN)
  { f32x4 a0[4] = {}, a1[4] = {};
    gemm32<4,4>(a0, a1, H, 136, P.wt + OFF_E + ntb*128, 128, 0, n0, q);
    #pragma unroll
    for (int nt = 0; nt < 4; ++nt) {
      const float bv = rbem[nt];
      #pragma unroll
      for (int r = 0; r < 4; ++r) { a0[nt][r] += bv; a1[nt][r] += bv; }
    }
    float mn[2][4], iv[2][4];
    #pragma unroll
    for (int s = 0; s < 2; ++s) {
      const f32x4* A_ = s ? a1 : a0;
      #pragma unroll
      for (int r = 0; r < 4; ++r) {
        float se = 0.f, qe = 0.f;
        #pragma unroll
        for (int t = 0; t < 4; ++t) { const float x = A_[t][r]; se += x; qe = fmaf(x,x,qe); }
        #pragma unroll
        for (int msk = 1; msk < 16; msk <<= 1) {
          se += __shfl_xor(se, msk, 64);
          qe += __shfl_xor(qe, msk, 64);
        }
        const float me = se*(1.f/64.f);
        mn[s][r] = me;
        iv[s][r] = 1.f / sqrtf(qe*(1.f/64.f) - me*me + 1e-5f);
      }
    }
    #pragma unroll
    for (int t = 0; t < 4; ++t) {
      const float g  = rg[t];
      const float be = rbe[t];
      const int col = ntb + t*16 + n0;
      #pragma unroll
      for (int s = 0; s < 2; ++s) {
        const f32x4* A_ = s ? a1 : a0;
        #pragma unroll
        for (int r = 0; r < 4; ++r) {
          float v = (A_[t][r] - mn[s][r])*iv[s][r]*g + be;
          v = fmaxf(v, 0.f);
          HL[(s*16 + q*4 + r)*136 + col] = f2bf(v);
        }
      }
    }
  }
  __syncthreads();

  // ---- fused head l2 part1: k 0..127 (E,M); wave w owns BD output tile w
  f32x4 o0[1] = {}, o1[1] = {};
  gemm32<1,4>(o0, o1, HL, 136, P.wt + OFF_BD + wave*16*288, 288, 0, n0, q);

  // ---- head l1 phase C: wave0 = MAT, wave1 = S (OFF_MAT..OFF_S contiguous)
  { f32x4 a0[4] = {}, a1[4] = {};
    gemm32<4,4>(a0, a1, H, 136, P.wt + OFF_MAT + ntb*128, 128, 0, n0, q);
    __syncthreads();   // all BD1 HL reads done before overwrite
    #pragma unroll
    for (int t = 0; t < 4; ++t) {
      const float bv = rbms[t];
      const int col = ntb + t*16 + n0;
      #pragma unroll
      for (int s = 0; s < 2; ++s) {
        const f32x4* A_ = s ? a1 : a0;
        #pragma unroll
        for (int r = 0; r < 4; ++r)
          HL[(s*16 + q*4 + r)*136 + col] = f2bf(fmaxf(A_[t][r] + bv, 0.f));
      }
    }
  }
  __syncthreads();

  // ---- fused head l2 part2: k 128..255 (MAT,S), accumulate
  gemm32<1,4>(o0, o1, HL, 136, P.wt + OFF_BD + wave*16*288, 288, 128, n0, q);

  // ---- head l1 phase B: P, wave w computes tile w -> HL cols w*16..w*16+15
  { f32x4 a0[1] = {}, a1[1] = {};
    gemm32<1,4>(a0, a1, H, 136, P.wt + OFF_P + wave*16*128, 128, 0, n0, q);
    __syncthreads();   // all BD2 HL reads done before overwrite
    const int col = wave*16 + n0;
    #pragma unroll
    for (int s = 0; s < 2; ++s) {
      const f32x4* A_ = s ? a1 : a0;
      #pragma unroll
      for (int r = 0; r < 4; ++r)
        HL[(s*16 + q*4 + r)*136 + col] = f2bf(fmaxf(A_[0][r] + rpb, 0.f));
    }
  }
  __syncthreads();

  // ---- fused head l2 part3: k 256..287 (P), accumulate
  gemm32<1,1>(o0, o1, HL, 136, P.wt + OFF_BD + wave*16*288, 288, 256, n0, q);
  __syncthreads();   // BD3 HL reads done before R2 (aliases HL) is written

  // l2 epilogue: wave0 tile -> j=n0 (0..15), wave1 tile -> j=16+n0 (n0<3)
  #pragma unroll
  for (int s = 0; s < 2; ++s) {
    const f32x4* O_ = s ? o1 : o0;
    #pragma unroll
    for (int r = 0; r < 4; ++r) {
      const int p = s*16 + q*4 + r;
      if (wave == 0) {
        float v0 = O_[0][r] + rc;
        if (n0 < 6) v0 = tanhf(v0);
        R2[p*20 + n0] = v0;
      } else if (n0 < 3) {
        R2[p*20 + 16 + n0] = O_[0][r] + rc;
      }
    }
  }
  __syncthreads();

  // ---- final packing (TIME=0 -> cos(phases))
  if (tid < 32) {
    const int gp2 = p0 + tid;
    if (gp2 < P.N) {
      const float* r = R2 + tid*20;
      float* o = P.out + (size_t)gp2*13;
      o[0] = r[0]*cosf(r[6]);
      o[1] = r[1]*cosf(r[7]);
      o[2] = r[2]*cosf(r[8]);
      o[3] = r[3]*cosf(r[9]);
      o[4] = r[4]*cosf(r[10]);
      o[5] = r[5]*cosf(r[11]);
      o[6] = 1.f + sigmoid_(r[12])*10.f;
      o[7] = 1.f + sigmoid_(r[13])*2.f;
      o[8] = sigmoid_(r[14])*0.01f;
      o[9]  = r[15];
      o[10] = r[16];
      o[11] = r[17];
      o[12] = r[18];
    }
  }
}

// ================= fallback fused kernel (ws too small) =================
__global__ __launch_bounds__(256, 3)
void em_nerf_fallback(Params P)
{
  __shared__ __align__(16) char smem[44288];
  short* featB = (short*)smem;
  short* hA    = (short*)(smem + 9216);
  short* hB    = (short*)(smem + 9216 + 17664);
  float* headF = (float*)(smem + 9216);
  float* res2  = (float*)smem;
  __shared__ int s_res[16];

  const int tid = threadIdx.x;
  if (tid < 16) s_res[tid] = P.res[tid];
  __syncthreads();
  {
    const int p = tid & 63;
    const int g = tid >> 6;
    int gp = blockIdx.x*64 + p; if (gp >= P.N) gp = P.N - 1;
    const float xs0 = fminf(fmaxf(P.x[gp*3+0], 0.f), 1.f);
    const float xs1 = fminf(fmaxf(P.x[gp*3+1], 0.f), 1.f);
    const float xs2 = fminf(fmaxf(P.x[gp*3+2], 0.f), 1.f);
    #pragma unroll
    for (int j = 0; j < 4; ++j) {
      const int l = g*4 + j;
      const int res = s_res[l];
      const float rf = (float)(res-1);
      const float s0 = xs0*rf, s1 = xs1*rf, s2 = xs2*rf;
      int f0i = (int)s0; if (f0i > res-1) f0i = res-1;
      int f1i = (int)s1; if (f1i > res-1) f1i = res-1;
      int f2i = (int)s2; if (f2i > res-1) f2i = res-1;
      const float w0 = s0 - (float)f0i;
      const float w1 = s1 - (float)f1i;
      const float w2 = s2 - (float)f2i;
      int c0i = f0i+1; if (c0i > res-1) c0i = res-1;
      int c1i = f1i+1; if (c1i > res-1) c1i = res-1;
      int c2i = f2i+1; if (c2i > res-1) c2i = res-1;
      const int hx0 = (f0i*PM0) & TMASK, hx1 = (c0i*PM0) & TMASK;
      const int hy0 = (f1i*PM1) & TMASK, hy1 = (c1i*PM1) & TMASK;
      const int hz0 = (f2i*PM2) & TMASK, hz1 = (c2i*PM2) & TMASK;
      const float* tp = P.tables + ((size_t)l << 20);
      float a0 = 0.f, a1 = 0.f;
      #pragma unroll
      for (int cn = 0; cn < 8; ++cn) {
        const int bx = (cn>>2)&1, by = (cn>>1)&1, bz = cn&1;
        const int hh = ((bx?hx1:hx0) + (by?hy1:hy0) + (bz?hz1:hz0)) & TMASK;
        const float cw = (bx?w0:1.f-w0)*(by?w1:1.f-w1)*(bz?w2:1.f-w2);
        const float2 tv = *(const float2*)(tp + 2*hh);
        a0 = fmaf(cw, tv.x, a0);
        a1 = fmaf(cw, tv.y, a1);
      }
      featB[p*72 + 2*l]   = f2bf(a0);
      featB[p*72 + 2*l+1] = f2bf(a1);
    }
    if (g == 0) {
      float fr = P.freq[gp];
      fr = fminf(fmaxf(fr, 1e6f), 1e12f);
      const float nf = (log10f(fr) - 6.f) * (1.f/6.f);
      float a = 3.14159274101257324f * nf;
      #pragma unroll
      for (int i = 0; i < 10; ++i) {
        featB[p*72 + 32 + 2*i] = f2bf(sinf(a));
        featB[p*72 + 33 + 2*i] = f2bf(cosf(a));
        a = a * 2.f;
      }
    }
    if (g == 3) {
      #pragma unroll
      for (int k = 52; k < 64; ++k) featB[p*72 + k] = 0;
    }
  }
  __syncthreads();

  const int lane = tid & 63, wave = tid >> 6;
  const int n0 = lane & 15, q = lane >> 4;
  short* myA  = featB + wave*16*72;
  short* myH1 = hA + wave*16*136;
  short* myH2 = hB + wave*16*136;

  auto gemm1 = [&](const short* A, int lda, const short* wt, int kpad, int kwoff, int KC, f32x4* acc, int NT){
    const short* Ap = A + n0*lda + q*8;
    const short* Bp = wt + n0*kpad + kwoff + q*8;
    for (int kc = 0; kc < KC; ++kc) {
      bf16x8 a = *(const bf16x8*)(Ap + kc*32);
      for (int nt = 0; nt < NT; ++nt) {
        bf16x8 b = *(const bf16x8*)(Bp + nt*16*kpad + kc*32);
        acc[nt] = __builtin_amdgcn_mfma_f32_16x16x32_bf16(a, b, acc[nt], 0, 0, 0);
      }
    }
  };
  auto epi1 = [&](const f32x4* acc, const float* bias, short* out, int ldo, int NT, bool relu){
    for (int nt = 0; nt < NT; ++nt) {
      const float bv = bias[nt*16 + n0];
      for (int r = 0; r < 4; ++r) {
        float v = acc[nt][r] + bv;
        if (relu) v = fmaxf(v, 0.f);
        out[(q*4 + r)*ldo + nt*16 + n0] = f2bf(v);
      }
    }
  };

  { f32x4 acc[8] = {}; gemm1(myA, 72, P.wt + OFF_W0, 64, 0, 2, acc, 8);  epi1(acc, P.b0, myH1, 136, 8, true); }
  __syncthreads();
  { f32x4 acc[8] = {}; gemm1(myH1, 136, P.wt + OFF_W1, 128, 0, 4, acc, 8); epi1(acc, P.b1, myH2, 136, 8, true); }
  __syncthreads();
  { f32x4 acc[8] = {}; gemm1(myH2, 136, P.wt + OFF_W2, 192, 0, 4, acc, 8);
    gemm1(myA, 72, P.wt + OFF_W2, 192, 128, 2, acc, 8); epi1(acc, P.b2, myH1, 136, 8, true); }
  __syncthreads();
  { f32x4 acc[8] = {}; gemm1(myH1, 136, P.wt + OFF_W3, 128, 0, 4, acc, 8); epi1(acc, P.b3, myH2, 136, 8, true); }
  __syncthreads();

  float* hf = headF + wave*16*69;
  auto head1f = [&](const short* wt, const float* bias, int NT, bool relu){
    f32x4 acc[4] = {};
    gemm1(myH2, 136, wt, 128, 0, 4, acc, NT);
    for (int nt = 0; nt < NT; ++nt) {
      const float bv = bias[nt*16 + n0];
      for (int r = 0; r < 4; ++r) {
        float v = acc[nt][r] + bv;
        if (relu) v = fmaxf(v, 0.f);
        hf[(q*4 + r)*69 + nt*16 + n0] = v;
      }
    }
  };
  auto l2 = [&](int OC2, int K2, bool ln, bool th, const float* g, const float* be,
                const float* W2, const float* b2, int slot){
    __syncthreads();
    if (tid < 64) {
      const float* row = headF + tid*69;
      float mn = 0.f, iv = 1.f;
      if (ln) {
        float s = 0.f;
        for (int k = 0; k < K2; ++k) s += row[k];
        mn = s/(float)K2;
        float vv = 0.f;
        for (int k = 0; k < K2; ++k) { float d = row[k]-mn; vv = fmaf(d,d,vv); }
        iv = 1.f/sqrtf(vv/(float)K2 + 1e-5f);
      }
      for (int j = 0; j < OC2; ++j) {
        float acc = b2[j];
        for (int k = 0; k < K2; ++k) {
          float xv = row[k];
          if (ln) xv = (xv-mn)*iv*g[k] + be[k];
          xv = fmaxf(xv, 0.f);
          acc = fmaf(xv, W2[k*OC2+j], acc);
        }
        res2[tid*20 + slot + j] = th ? tanhf(acc) : acc;
      }
    }
    __syncthreads();
  };

  head1f(P.wt + OFF_E, P.e_b1, 4, false); l2(3, 64, true,  true,  P.e_g, P.e_be, P.e_w2, P.e_b2, 0);
  head1f(P.wt + OFF_E + 8192, P.m_b1, 4, false); l2(3, 64, true, true, P.m_g, P.m_be, P.m_w2, P.m_b2, 3);
  head1f(P.wt + OFF_P, P.p_b1, 2, true);  l2(6, 32, false, false, 0, 0, P.p_w2, P.p_b2, 6);
  head1f(P.wt + OFF_MAT, P.mat_b1, 4, true); l2(3, 64, false, false, 0, 0, P.mat_w2, P.mat_b2, 12);
  head1f(P.wt + OFF_S, P.s_b1, 4, true);  l2(4, 64, false, false, 0, 0, P.s_w2, P.s_b2, 15);

  if (tid < 64) {
    const int gp = blockIdx.x*64 + tid;
    if (gp < P.N) {
      const float* r = res2 + tid*20;
      float* o = P.out + (size_t)gp*13;
      o[0] = r[0]*cosf(r[6]);
      o[1] = r[1]*cosf(r[7]);
      o[2] = r[2]*cosf(r[8]);
      o[3] = r[3]*cosf(r[9]);
      o[4] = r[4]*cosf(r[10]);
      o[5] = r[5]*cosf(r[11]);
      o[6] = 1.f + sigmoid_(r[12])*10.f;
      o[7] = 1.f + sigmoid_(r[13])*2.f;
      o[8] = sigmoid_(r[14])*0.01f;
      o[9]  = r[15];
      o[10] = r[16];
      o[11] = r[17];
      o[12] = r[18];
    }
  }
}

extern "C" void kernel_launch(void* const* d_in, const int* in_sizes, int n_in,
                              void* d_out, int out_size, void* d_ws, size_t ws_size,
                              hipStream_t stream) {
  (void)n_in; (void)out_size;
  const float** in = (const float**)d_in;
  const int N = in_sizes[0] / 3;

  PrepParams PP;
  const float* srcs[9] = { in[3], in[5], in[7], in[9], in[11], in[15], in[19], in[23], in[27] };
  const int ends[9]  = { 8192, 24576, 49152, 65536, 73728, 81920, 86016, 94208, 102400 };
  const int nsrc[9]  = { 128, 128, 128, 128, 64, 64, 32, 64, 64 };
  const int ksrc[9]  = { 52, 128, 180, 128, 128, 128, 128, 128, 128 };
  const int kpad[9]  = { 64, 128, 192, 128, 128, 128, 128, 128, 128 };
  for (int i = 0; i < 9; ++i) { PP.src[i]=srcs[i]; PP.end[i]=ends[i]; PP.Nsrc[i]=nsrc[i]; PP.Ksrc[i]=ksrc[i]; PP.Kpad[i]=kpad[i]; }
  PP.wt = (short*)d_ws;
  hipLaunchKernelGGL(prep_weights, dim3((WT_TOTAL+255)/256), dim3(256), 0, stream, PP);

  BdParams BP;
  BP.e = in[13]; BP.m = in[17]; BP.p = in[21]; BP.mat = in[25]; BP.s = in[29];
  BP.out = (short*)d_ws + OFF_BD;
  hipLaunchKernelGGL(prep_bd, dim3((32*288 + 255)/256), dim3(256), 0, stream, BP);

  Params P;
  P.x = in[0]; P.freq = in[1]; P.tables = in[2];
  P.b0 = in[4]; P.b1 = in[6]; P.b2 = in[8]; P.b3 = in[10];
  P.e_b1 = in[12]; P.e_w2 = in[13]; P.e_b2 = in[14];
  P.m_b1 = in[16]; P.m_w2 = in[17]; P.m_b2 = in[18];
  P.p_b1 = in[20]; P.p_w2 = in[21]; P.p_b2 = in[22];
  P.mat_b1 = in[24]; P.mat_w2 = in[25]; P.mat_b2 = in[26];
  P.s_b1 = in[28]; P.s_w2 = in[29]; P.s_b2 = in[30];
  P.e_g = in[31]; P.e_be = in[32]; P.m_g = in[33]; P.m_be = in[34];
  P.wt = (const short*)d_ws;
  P.feat = (const unsigned*)((const char*)d_ws + WS_FEAT_OFF);
  P.out = (float*)d_out;
  P.N = N;

  const double B = exp((log(512.0) - log(16.0)) / 15.0);
  for (int l = 0; l < 16; ++l) {
    double r = 16.0 * pow(B, (double)l);
    int ri = (int)r;
    if (ri > 512) ri = 512;
    P.res[l] = ri;
  }

  const size_t feat_bytes = (size_t)N*8*4;
  const size_t need = (size_t)WS_FEAT_OFF + feat_bytes + DENSE_BYTES;

  if (ws_size >= need) {
    char* dense_base = (char*)d_ws + WS_FEAT_OFF + feat_bytes;
    P.dense = (const unsigned short*)dense_base;

    TabPrepParams TP;
    TP.tables = in[2];
    TP.tab8 = (unsigned*)((char*)d_ws + WS_TAB8_OFF);
    hipLaunchKernelGGL(tab_prep, dim3((16*524288/2 + 255)/256), dim3(256), 0, stream, TP);

    DensePrepParams DP;
    DP.tab8 = (const unsigned short*)((const char*)d_ws + WS_TAB8_OFF);
    DP.dense = (unsigned short*)dense_base;
    hipLaunchKernelGGL(dense_prep8, dim3((DENSE_USHORTS + 255)/256), dim3(256), 0, stream, DP);

    HashParams HP;
    HP.x = in[0];
    HP.tab8 = (const unsigned short*)((const char*)d_ws + WS_TAB8_OFF);
    HP.feat = (unsigned*)((char*)d_ws + WS_FEAT_OFF);
    HP.N = N;
    for (int l = 0; l < 16; ++l) HP.res[l] = P.res[l];
    const int strips = (N + 511) / 512;
    hipLaunchKernelGGL(hash_encode8u, dim3(strips*8), dim3(256), 0, stream, HP);

    hipLaunchKernelGGL(em_nerf6, dim3((N + 31) / 32), dim3(128), 0, stream, P);
  } else {
    P.dense = nullptr;
    hipLaunchKernelGGL(em_nerf_fallback, dim3((N + 63) / 64), dim3(256), 0, stream, P);
  }
}

// Round 14
// 467.584 us; speedup vs baseline: 1.1426x; 1.1426x over previous
//
#include <hip/hip_runtime.h>
#include <math.h>

#define TMASK 524287   // 2^19 - 1
#define PM0 455773     // 73856093 % 2^19
#define PM1 475295     // 19349663 % 2^19
#define PM2 130999     // 83492791 % 2^19

typedef __attribute__((ext_vector_type(8))) short bf16x8;
typedef __attribute__((ext_vector_type(4))) float f32x4;

// Transposed-bf16 weight buffer layout in d_ws (element offsets, shorts):
#define OFF_W0   0       // [128][64]   (K=52  pad 64)
#define OFF_W1   8192    // [128][128]
#define OFF_W2   24576   // [128][192]  (K=180 pad 192)
#define OFF_W3   49152   // [128][128]
#define OFF_E    65536   // [64][128]   E,M contiguous (8 tiles)
#define OFF_P    81920   // [32][128]
#define OFF_MAT  86016   // [64][128]   MAT,S contiguous (8 tiles)
#define OFF_S    94208   // [64][128]
#define OFF_BD   102400  // [32][288] block-diagonal fused head-l2 matrix, k-order E|M|MAT|S|P
#define WT_TOTAL 102400
#define WT_ALLOC 111616  // + BD region

// ws byte layout: wt | tab8 int8[16][524288][2] (16 MiB) | feat uint[8][N] | dense
#define WS_TAB8_OFF (WT_ALLOC*2)
#define TAB8_BYTES  (16u*524288u*2u)
#define WS_FEAT_OFF (WS_TAB8_OFF + TAB8_BYTES)
// dense tables levels 0-7 (res 16/20/25/32/40/50/64/80), ushort entries.
// ushort offs {0,4096,12096,27728,60496,124496,249496,511640}, total 1023640
#define DENSE_USHORTS 1023640
#define DENSE_BYTES   (DENSE_USHORTS*2)

#define TAB_SCALE   131072.0f
#define TAB_INV     (1.0f/131072.0f)

// ---- MLP LDS layout: ONE shared arena (N-split: both waves, same 32 pts)
#define A6_H    0        // bf16[32][136]
#define A6_HL   8704     // bf16[32][136]
#define A6_FB   8704     // bf16[32][72] aliases HL (dead before HL written)
                         // R2 f32[32][20] aliases too (written after BD3)
#define LDS6_TOTAL 17408

struct Params {
  const float* x; const float* freq; const float* tables;
  const float* b0; const float* b1; const float* b2; const float* b3;
  const float* e_b1; const float* e_w2; const float* e_b2; const float* e_g; const float* e_be;
  const float* m_b1; const float* m_w2; const float* m_b2; const float* m_g; const float* m_be;
  const float* p_b1; const float* p_w2; const float* p_b2;
  const float* mat_b1; const float* mat_w2; const float* mat_b2;
  const float* s_b1; const float* s_w2; const float* s_b2;
  const short* wt;
  const unsigned* feat;        // [8][N] level-major (levels 8..15)
  const unsigned short* dense; // levels 0..7 direct-indexed
  float* out;
  int N;
  int res[16];
};

struct HashParams {
  const float* x; const unsigned short* tab8; unsigned* feat; int N; int res[16];
};
struct DensePrepParams { const unsigned short* tab8; unsigned short* dense; };
struct TabPrepParams { const float* tables; unsigned* tab8; };
struct PrepParams {
  const float* src[9];
  int end[9]; int Nsrc[9]; int Ksrc[9]; int Kpad[9];
  short* wt;
};
struct BdParams {
  const float* e; const float* m; const float* p; const float* mat; const float* s;
  short* out;
};

__device__ __forceinline__ short f2bf(float f){
  union { float f; unsigned u; } v; v.f = f;
  unsigned r = v.u + 0x7fffu + ((v.u >> 16) & 1u);   // RNE
  return (short)(r >> 16);
}
__device__ __forceinline__ float bf2f(short s){
  union { unsigned u; float f; } v; v.u = ((unsigned)(unsigned short)s) << 16; return v.f;
}
__device__ __forceinline__ float sigmoid_(float v){ return 1.f/(1.f + expf(-v)); }

// ---------------- weight transpose+bf16 prep
__global__ __launch_bounds__(256)
void prep_weights(PrepParams P)
{
  int id = blockIdx.x*256 + threadIdx.x;
  if (id >= WT_TOTAL) return;
  int r = 0, base = 0;
  #pragma unroll
  for (int i = 0; i < 9; ++i) { if (id >= P.end[i]) { r = i+1; base = P.end[i]; } }
  const int rel = id - base;
  const int kp = P.Kpad[r];
  const int n = rel / kp;
  const int k = rel - n*kp;
  float v = 0.f;
  if (k < P.Ksrc[r]) v = P.src[r][k * P.Nsrc[r] + n];
  P.wt[id] = f2bf(v);
}

// ---------------- block-diagonal fused head-l2 matrix [32 n][288 k]
// k-order: E 0..63 | M 64..127 | MAT 128..191 | S 192..255 | P 256..287
__global__ __launch_bounds__(256)
void prep_bd(BdParams P)
{
  int id = blockIdx.x*256 + threadIdx.x;
  if (id >= 32*288) return;
  const int n = id / 288, k = id - n*288;
  float v = 0.f;
  if      (n < 3  && k < 64)                        v = P.e[k*3 + n];
  else if (n >= 3 && n < 6  && k >= 64  && k < 128) v = P.m[(k-64)*3 + (n-3)];
  else if (n >= 6 && n < 12 && k >= 256)            v = P.p[(k-256)*6 + (n-6)];
  else if (n >= 12&& n < 15 && k >= 128 && k < 192) v = P.mat[(k-128)*3 + (n-12)];
  else if (n >= 15&& n < 19 && k >= 192 && k < 256) v = P.s[(k-192)*4 + (n-15)];
  P.out[id] = f2bf(v);
}

// ---------------- table quantize fp32 -> int8 (scale 2^17)
__global__ __launch_bounds__(256)
void tab_prep(TabPrepParams P)
{
  const unsigned id = blockIdx.x*256 + threadIdx.x;
  if (id >= 16u*524288u/2u) return;
  const float4 v = ((const float4*)P.tables)[id];
  int q0 = (int)fminf(fmaxf(rintf(v.x*TAB_SCALE), -127.f), 127.f);
  int q1 = (int)fminf(fmaxf(rintf(v.y*TAB_SCALE), -127.f), 127.f);
  int q2 = (int)fminf(fmaxf(rintf(v.z*TAB_SCALE), -127.f), 127.f);
  int q3 = (int)fminf(fmaxf(rintf(v.w*TAB_SCALE), -127.f), 127.f);
  unsigned pack = (q0 & 255) | ((q1 & 255) << 8) | ((q2 & 255) << 16) | ((q3 & 255) << 24);
  P.tab8[id] = pack;
}

// ---------------- densify levels 0-7 (res 16..80) from tab8
// dense[l][(cx*res+cy)*res+cz] = tab8[l][hash(cx,cy,cz)] -- identical values.
__global__ __launch_bounds__(256)
void dense_prep8(DensePrepParams P)
{
  const int id = blockIdx.x*256 + threadIdx.x;
  if (id >= DENSE_USHORTS) return;
  int l = 0, base = 0, res = 16;
  if (id >= 4096)   { l = 1; base = 4096;   res = 20; }
  if (id >= 12096)  { l = 2; base = 12096;  res = 25; }
  if (id >= 27728)  { l = 3; base = 27728;  res = 32; }
  if (id >= 60496)  { l = 4; base = 60496;  res = 40; }
  if (id >= 124496) { l = 5; base = 124496; res = 50; }
  if (id >= 249496) { l = 6; base = 249496; res = 64; }
  if (id >= 511640) { l = 7; base = 511640; res = 80; }
  const int c = id - base;
  if (c >= res*res*res) return;   // pad gap (level 2)
  const int cz = c % res;
  const int t  = c / res;
  const int cy = t % res;
  const int cx = t / res;
  const unsigned h = (unsigned)((cx*PM0 + cy*PM1 + cz*PM2) & TMASK);
  P.dense[id] = P.tab8[((unsigned)l << 19) + h];
}

// ---------------- per-XCD fine hash, levels 8..15, 2 pts/thread.
// 8 units = 8 levels; unit = b%8 -> XCD = b%8 = level: each XCD owns ONE 1MB
// level table (fully L2-resident) and all N points for it. Regular loads
// (R13 lesson: nontemporal bypassed L2 -> every gather went to HBM).
__global__ __launch_bounds__(256, 8)
void hash_encode8u(HashParams P)
{
  const int b = blockIdx.x;
  const int l = 8 + (b & 7);
  const int strip = b >> 3;
  const int pA = strip*512 + threadIdx.x;
  if (pA >= P.N) return;
  const int pB0 = pA + 256;
  const bool sB = pB0 < P.N;
  const int pB = sB ? pB0 : pA;

  const int res = P.res[l];
  const float rf = (float)(res-1);
  const unsigned short* tp = P.tab8 + ((size_t)l << 19);

  const float xA0 = fminf(fmaxf(P.x[pA*3+0], 0.f), 1.f);
  const float xA1 = fminf(fmaxf(P.x[pA*3+1], 0.f), 1.f);
  const float xA2 = fminf(fmaxf(P.x[pA*3+2], 0.f), 1.f);
  const float sA0 = xA0*rf, sA1 = xA1*rf, sA2 = xA2*rf;
  int fA0 = (int)sA0; if (fA0 > res-1) fA0 = res-1;
  int fA1 = (int)sA1; if (fA1 > res-1) fA1 = res-1;
  int fA2 = (int)sA2; if (fA2 > res-1) fA2 = res-1;
  const float wA0 = sA0 - (float)fA0;
  const float wA1 = sA1 - (float)fA1;
  const float wA2 = sA2 - (float)fA2;
  int cA0 = fA0+1; if (cA0 > res-1) cA0 = res-1;
  int cA1 = fA1+1; if (cA1 > res-1) cA1 = res-1;
  int cA2 = fA2+1; if (cA2 > res-1) cA2 = res-1;
  const int hxA0 = (fA0*PM0) & TMASK, hxA1 = (cA0*PM0) & TMASK;
  const int hyA0 = (fA1*PM1) & TMASK, hyA1 = (cA1*PM1) & TMASK;
  const int hzA0 = (fA2*PM2) & TMASK, hzA1 = (cA2*PM2) & TMASK;

  const float xB0 = fminf(fmaxf(P.x[pB*3+0], 0.f), 1.f);
  const float xB1 = fminf(fmaxf(P.x[pB*3+1], 0.f), 1.f);
  const float xB2 = fminf(fmaxf(P.x[pB*3+2], 0.f), 1.f);
  const float sB0 = xB0*rf, sB1 = xB1*rf, sB2 = xB2*rf;
  int fB0 = (int)sB0; if (fB0 > res-1) fB0 = res-1;
  int fB1 = (int)sB1; if (fB1 > res-1) fB1 = res-1;
  int fB2 = (int)sB2; if (fB2 > res-1) fB2 = res-1;
  const float wB0 = sB0 - (float)fB0;
  const float wB1 = sB1 - (float)fB1;
  const float wB2 = sB2 - (float)fB2;
  int cB0 = fB0+1; if (cB0 > res-1) cB0 = res-1;
  int cB1 = fB1+1; if (cB1 > res-1) cB1 = res-1;
  int cB2 = fB2+1; if (cB2 > res-1) cB2 = res-1;
  const int hxB0 = (fB0*PM0) & TMASK, hxB1 = (cB0*PM0) & TMASK;
  const int hyB0 = (fB1*PM1) & TMASK, hyB1 = (cB1*PM1) & TMASK;
  const int hzB0 = (fB2*PM2) & TMASK, hzB1 = (cB2*PM2) & TMASK;

  // 16 gathers in flight
  unsigned short tvA[8], tvB[8];
  #pragma unroll
  for (int cn = 0; cn < 8; ++cn) {
    const int bx = (cn>>2)&1, by = (cn>>1)&1, bz = cn&1;
    tvA[cn] = tp[((bx?hxA1:hxA0) + (by?hyA1:hyA0) + (bz?hzA1:hzA0)) & TMASK];
    tvB[cn] = tp[((bx?hxB1:hxB0) + (by?hyB1:hyB0) + (bz?hzB1:hzB0)) & TMASK];
  }

  unsigned* fl = P.feat + (size_t)(l-8)*P.N;
  {
    float a0 = 0.f, a1 = 0.f;
    #pragma unroll
    for (int cn = 0; cn < 8; ++cn) {
      const int bx = (cn>>2)&1, by = (cn>>1)&1, bz = cn&1;
      const float cw = (bx?wA0:1.f-wA0)*(by?wA1:1.f-wA1)*(bz?wA2:1.f-wA2);
      a0 = fmaf(cw, (float)(int)(signed char)(tvA[cn] & 0xff), a0);
      a1 = fmaf(cw, (float)(int)(signed char)(tvA[cn] >> 8),   a1);
    }
    a0 *= TAB_INV; a1 *= TAB_INV;
    fl[pA] = (unsigned)(unsigned short)f2bf(a0)
           | ((unsigned)(unsigned short)f2bf(a1) << 16);
  }
  if (sB) {
    float a0 = 0.f, a1 = 0.f;
    #pragma unroll
    for (int cn = 0; cn < 8; ++cn) {
      const int bx = (cn>>2)&1, by = (cn>>1)&1, bz = cn&1;
      const float cw = (bx?wB0:1.f-wB0)*(by?wB1:1.f-wB1)*(bz?wB2:1.f-wB2);
      a0 = fmaf(cw, (float)(int)(signed char)(tvB[cn] & 0xff), a0);
      a1 = fmaf(cw, (float)(int)(signed char)(tvB[cn] >> 8),   a1);
    }
    a0 *= TAB_INV; a1 *= TAB_INV;
    fl[pB] = (unsigned)(unsigned short)f2bf(a0)
           | ((unsigned)(unsigned short)f2bf(a1) << 16);
  }
}

// ---------------- dense trilinear blend helper (direct-indexed table)
__device__ __forceinline__ unsigned dense_blend(
    const unsigned short* __restrict__ dp, int res,
    float xs0, float xs1, float xs2)
{
  const float rf = (float)(res-1);
  const float s0 = xs0*rf, s1 = xs1*rf, s2 = xs2*rf;
  int f0i = (int)s0; if (f0i > res-1) f0i = res-1;
  int f1i = (int)s1; if (f1i > res-1) f1i = res-1;
  int f2i = (int)s2; if (f2i > res-1) f2i = res-1;
  const float w0 = s0 - (float)f0i;
  const float w1 = s1 - (float)f1i;
  const float w2 = s2 - (float)f2i;
  int c0i = f0i+1; if (c0i > res-1) c0i = res-1;
  int c1i = f1i+1; if (c1i > res-1) c1i = res-1;
  int c2i = f2i+1; if (c2i > res-1) c2i = res-1;
  const int sx0 = f0i*res*res, sx1 = c0i*res*res;
  const int ty0 = f1i*res,     ty1 = c1i*res;
  unsigned short tv[8];
  #pragma unroll
  for (int cn = 0; cn < 8; ++cn) {
    const int bx = (cn>>2)&1, by = (cn>>1)&1, bz = cn&1;
    tv[cn] = dp[(bx?sx1:sx0) + (by?ty1:ty0) + (bz?c2i:f2i)];
  }
  float a0 = 0.f, a1 = 0.f;
  #pragma unroll
  for (int cn = 0; cn < 8; ++cn) {
    const int bx = (cn>>2)&1, by = (cn>>1)&1, bz = cn&1;
    const float cw = (bx?w0:1.f-w0)*(by?w1:1.f-w1)*(bz?w2:1.f-w2);
    a0 = fmaf(cw, (float)(int)(signed char)(tv[cn] & 0xff), a0);
    a1 = fmaf(cw, (float)(int)(signed char)(tv[cn] >> 8),   a1);
  }
  a0 *= TAB_INV; a1 *= TAB_INV;
  return (unsigned)(unsigned short)f2bf(a0)
       | ((unsigned)(unsigned short)f2bf(a1) << 16);
}

// ---------------- M=32 MFMA phase with depth-1 B prefetch (ping-pong regs)
template<int NT, int KC>
__device__ __forceinline__ void gemm32(f32x4* acc0, f32x4* acc1,
    const short* A, int lda, const short* __restrict__ wt, int kpad, int kwoff,
    int n0, int q)
{
  const short* Ap0 = A + n0*lda + q*8;
  const short* Ap1 = Ap0 + 16*lda;
  const short* Bp  = wt + n0*kpad + kwoff + q*8;
  bf16x8 bc[NT], bn[NT];
  #pragma unroll
  for (int nt = 0; nt < NT; ++nt) bc[nt] = *(const bf16x8*)(Bp + nt*16*kpad);
  #pragma unroll
  for (int kc = 0; kc < KC; ++kc) {
    if (kc + 1 < KC) {
      #pragma unroll
      for (int nt = 0; nt < NT; ++nt)
        bn[nt] = *(const bf16x8*)(Bp + nt*16*kpad + (kc+1)*32);
    }
    const bf16x8 a0 = *(const bf16x8*)(Ap0 + kc*32);
    const bf16x8 a1 = *(const bf16x8*)(Ap1 + kc*32);
    #pragma unroll
    for (int nt = 0; nt < NT; ++nt) {
      acc0[nt] = __builtin_amdgcn_mfma_f32_16x16x32_bf16(a0, bc[nt], acc0[nt], 0, 0, 0);
      acc1[nt] = __builtin_amdgcn_mfma_f32_16x16x32_bf16(a1, bc[nt], acc1[nt], 0, 0, 0);
    }
    #pragma unroll
    for (int nt = 0; nt < NT; ++nt) bc[nt] = bn[nt];
  }
}

// trunk epilogue: bias(reg) + relu + f2bf -> LDS (C: col=lane&15, row=(lane>>4)*4+reg)
template<int NT>
__device__ __forceinline__ void epi_trunk(const f32x4* acc0, const f32x4* acc1,
    const float* bv4, short* out, int ldo, int n0, int q, int coff)
{
  #pragma unroll
  for (int nt = 0; nt < NT; ++nt) {
    const float bv = bv4[nt];
    #pragma unroll
    for (int r = 0; r < 4; ++r) {
      float v0 = fmaxf(acc0[nt][r] + bv, 0.f);
      float v1 = fmaxf(acc1[nt][r] + bv, 0.f);
      out[(q*4 + r)*ldo + coff + nt*16 + n0]      = f2bf(v0);
      out[(16 + q*4 + r)*ldo + coff + nt*16 + n0] = f2bf(v1);
    }
  }
}

// N-split kernel (R10-best variant: constants loaded EARLY for prologue
// overlap; the mild spill it causes is absorbed by TLP and measured faster).
// Levels 0-7 inline from dense tables; levels 8-15 from feat[8][N].
__global__ __launch_bounds__(128, 4)
void em_nerf6(Params P)
{
  __shared__ __align__(16) char smem[LDS6_TOTAL];
  const int tid = threadIdx.x;
  const int lane = tid & 63, wave = tid >> 6;
  short* H  = (short*)(smem + A6_H);
  short* HL = (short*)(smem + A6_HL);
  short* FB = (short*)(smem + A6_FB);
  float* R2 = (float*)(smem + A6_HL);
  const int n0 = lane & 15, q = lane >> 4;
  const int p0 = blockIdx.x*32;
  const int ntb = wave*64;   // this wave's output-column base (4 tiles)

  // thread roles for staging: point pp = tid&31, group lg = tid>>5 (0..3)
  const int pp = tid & 31;
  const int lg = tid >> 5;
  int gp = p0 + pp; if (gp >= P.N) gp = P.N - 1;

  // hash-feat loads issued first: feat [8][N]; thread loads levels lg*2, lg*2+1
  unsigned fw2[2];
  #pragma unroll
  for (int j = 0; j < 2; ++j)
    fw2[j] = P.feat[(size_t)(lg*2 + j)*P.N + gp];

  // point coords (shared by coarse + mid dense blends)
  const float xs0 = fminf(fmaxf(P.x[gp*3+0], 0.f), 1.f);
  const float xs1 = fminf(fmaxf(P.x[gp*3+1], 0.f), 1.f);
  const float xs2 = fminf(fmaxf(P.x[gp*3+2], 0.f), 1.f);

  // per-lane constants -> VGPRs (independent loads; overlap gather latency)
  float rb0[4], rb1[4], rb2[4], rb3[4], rbem[4], rbms[4], rg[4], rbe[4];
  {
    const float* embp = wave ? P.m_b1 : P.e_b1;
    const float* msbp = wave ? P.s_b1 : P.mat_b1;
    const float* ggp  = wave ? P.m_g  : P.e_g;
    const float* bbep = wave ? P.m_be : P.e_be;
    #pragma unroll
    for (int nt = 0; nt < 4; ++nt) {
      const int c  = ntb + nt*16 + n0;
      const int ch = nt*16 + n0;
      rb0[nt] = P.b0[c]; rb1[nt] = P.b1[c]; rb2[nt] = P.b2[c]; rb3[nt] = P.b3[c];
      rbem[nt] = embp[ch]; rbms[nt] = msbp[ch];
      rg[nt] = ggp[ch]; rbe[nt] = bbep[ch];
    }
  }
  const float rpb = P.p_b1[wave*16 + n0];
  float rc;
  if (wave == 0) {
    if      (n0 < 3)  rc = P.e_b2[n0];
    else if (n0 < 6)  rc = P.m_b2[n0-3];
    else if (n0 < 12) rc = P.p_b2[n0-6];
    else if (n0 < 15) rc = P.mat_b2[n0-12];
    else              rc = P.s_b2[0];
  } else {
    rc = (n0 < 3) ? P.s_b2[1 + n0] : 0.f;
  }

  // coarse level lg (0..3) inline from dense
  unsigned coarse_pack;
  {
    const int lo  = (lg & 1) ? 20 : 16;
    const int hi  = (lg & 1) ? 32 : 25;
    const int res = (lg & 2) ? hi : lo;
    const unsigned dlo  = (lg & 1) ? 4096u  : 0u;
    const unsigned dhi  = (lg & 1) ? 27728u : 12096u;
    const unsigned doff = (lg & 2) ? dhi : dlo;
    coarse_pack = dense_blend(P.dense + doff, res, xs0, xs1, xs2);
  }

  // mid level 4+lg inline from dense (L2-resident ~2MB)
  unsigned mid_pack;
  {
    const int lo  = (lg & 1) ? 50 : 40;
    const int hi  = (lg & 1) ? 80 : 64;
    const int res = (lg & 2) ? hi : lo;
    const unsigned dlo  = (lg & 1) ? 124496u : 60496u;
    const unsigned dhi  = (lg & 1) ? 511640u : 249496u;
    const unsigned doff = (lg & 2) ? dhi : dlo;
    mid_pack = dense_blend(P.dense + doff, res, xs0, xs1, xs2);
  }

  // freq encode: 4 threads per point, bands i = lg, lg+4, ...
  {
    float fr = P.freq[gp];
    fr = fminf(fmaxf(fr, 1e6f), 1e12f);
    const float nf = (log10f(fr) - 6.f) * (1.f/6.f);
    const float a0 = 3.14159274101257324f * nf;
    #pragma clang loop unroll(disable)
    for (int i = lg; i < 10; i += 4) {
      const float a = a0 * (float)(1 << i);   // exact pow2 scale == iterative doubling
      FB[pp*72 + 32 + 2*i] = f2bf(sinf(a));
      FB[pp*72 + 33 + 2*i] = f2bf(cosf(a));
    }
    if (lg == 3) {
      #pragma unroll
      for (int k = 52; k < 64; ++k) FB[pp*72 + k] = 0;
    }
  }

  // FB words: coarse lg -> shorts [2lg,2lg+1]; mid 4+lg -> shorts [8+2lg,9+2lg];
  // hash levels 8+lg*2+j -> shorts [16+2*(lg*2+j) ...]
  *(unsigned*)&FB[pp*72 + 2*lg] = coarse_pack;
  *(unsigned*)&FB[pp*72 + 8 + 2*lg] = mid_pack;
  #pragma unroll
  for (int j = 0; j < 2; ++j)
    *(unsigned*)&FB[pp*72 + 16 + 4*lg + 2*j] = fw2[j];
  __syncthreads();

  // ---- trunk (each layer: gemm reads, barrier, epi writes, barrier)
  { f32x4 a0[4] = {}, a1[4] = {};
    gemm32<4,2>(a0, a1, FB, 72, P.wt + OFF_W0 + ntb*64, 64, 0, n0, q);
    // W0 writes H (first write) while other wave may still read FB: disjoint.
    epi_trunk<4>(a0, a1, rb0, H, 136, n0, q, ntb);
    __syncthreads(); }
  { f32x4 a0[4] = {}, a1[4] = {};
    gemm32<4,4>(a0, a1, H, 136, P.wt + OFF_W1 + ntb*128, 128, 0, n0, q);
    __syncthreads();
    epi_trunk<4>(a0, a1, rb1, H, 136, n0, q, ntb);
    __syncthreads(); }
  { f32x4 a0[4] = {}, a1[4] = {};
    gemm32<4,4>(a0, a1, H, 136, P.wt + OFF_W2 + ntb*192, 192, 0, n0, q);
    gemm32<4,2>(a0, a1, FB, 72, P.wt + OFF_W2 + ntb*192, 192, 128, n0, q);
    __syncthreads();
    epi_trunk<4>(a0, a1, rb2, H, 136, n0, q, ntb);
    __syncthreads(); }
  { f32x4 a0[4] = {}, a1[4] = {};
    gemm32<4,4>(a0, a1, H, 136, P.wt + OFF_W3 + ntb*128, 128, 0, n0, q);
    __syncthreads();
    epi_trunk<4>(a0, a1, rb3, H, 136, n0, q, ntb);
    __syncthreads(); }
  // FB dead from here; HL (aliasing FB region) becomes live.

  // ---- head l1 phase A: wave0 = E (4 tiles + LN), wave1 = M (4 tiles + LN)
  { f32x4 a0[4] = {}, a1[4] = {};
    gemm32<4,4>(a0, a1, H, 136, P.wt + OFF_E + ntb*128, 128, 0, n0, q);
    #pragma unroll
    for (int nt = 0; nt < 4; ++nt) {
      const float bv = rbem[nt];
      #pragma unroll
      for (int r = 0; r < 4; ++r) { a0[nt][r] += bv; a1[nt][r] += bv; }
    }
    float mn[2][4], iv[2][4];
    #pragma unroll
    for (int s = 0; s < 2; ++s) {
      const f32x4* A_ = s ? a1 : a0;
      #pragma unroll
      for (int r = 0; r < 4; ++r) {
        float se = 0.f, qe = 0.f;
        #pragma unroll
        for (int t = 0; t < 4; ++t) { const float x = A_[t][r]; se += x; qe = fmaf(x,x,qe); }
        #pragma unroll
        for (int msk = 1; msk < 16; msk <<= 1) {
          se += __shfl_xor(se, msk, 64);
          qe += __shfl_xor(qe, msk, 64);
        }
        const float me = se*(1.f/64.f);
        mn[s][r] = me;
        iv[s][r] = 1.f / sqrtf(qe*(1.f/64.f) - me*me + 1e-5f);
      }
    }
    #pragma unroll
    for (int t = 0; t < 4; ++t) {
      const float g  = rg[t];
      const float be = rbe[t];
      const int col = ntb + t*16 + n0;
      #pragma unroll
      for (int s = 0; s < 2; ++s) {
        const f32x4* A_ = s ? a1 : a0;
        #pragma unroll
        for (int r = 0; r < 4; ++r) {
          float v = (A_[t][r] - mn[s][r])*iv[s][r]*g + be;
          v = fmaxf(v, 0.f);
          HL[(s*16 + q*4 + r)*136 + col] = f2bf(v);
        }
      }
    }
  }
  __syncthreads();

  // ---- fused head l2 part1: k 0..127 (E,M); wave w owns BD output tile w
  f32x4 o0[1] = {}, o1[1] = {};
  gemm32<1,4>(o0, o1, HL, 136, P.wt + OFF_BD + wave*16*288, 288, 0, n0, q);

  // ---- head l1 phase C: wave0 = MAT, wave1 = S (OFF_MAT..OFF_S contiguous)
  { f32x4 a0[4] = {}, a1[4] = {};
    gemm32<4,4>(a0, a1, H, 136, P.wt + OFF_MAT + ntb*128, 128, 0, n0, q);
    __syncthreads();   // all BD1 HL reads done before overwrite
    #pragma unroll
    for (int t = 0; t < 4; ++t) {
      const float bv = rbms[t];
      const int col = ntb + t*16 + n0;
      #pragma unroll
      for (int s = 0; s < 2; ++s) {
        const f32x4* A_ = s ? a1 : a0;
        #pragma unroll
        for (int r = 0; r < 4; ++r)
          HL[(s*16 + q*4 + r)*136 + col] = f2bf(fmaxf(A_[t][r] + bv, 0.f));
      }
    }
  }
  __syncthreads();

  // ---- fused head l2 part2: k 128..255 (MAT,S), accumulate
  gemm32<1,4>(o0, o1, HL, 136, P.wt + OFF_BD + wave*16*288, 288, 128, n0, q);

  // ---- head l1 phase B: P, wave w computes tile w -> HL cols w*16..w*16+15
  { f32x4 a0[1] = {}, a1[1] = {};
    gemm32<1,4>(a0, a1, H, 136, P.wt + OFF_P + wave*16*128, 128, 0, n0, q);
    __syncthreads();   // all BD2 HL reads done before overwrite
    const int col = wave*16 + n0;
    #pragma unroll
    for (int s = 0; s < 2; ++s) {
      const f32x4* A_ = s ? a1 : a0;
      #pragma unroll
      for (int r = 0; r < 4; ++r)
        HL[(s*16 + q*4 + r)*136 + col] = f2bf(fmaxf(A_[0][r] + rpb, 0.f));
    }
  }
  __syncthreads();

  // ---- fused head l2 part3: k 256..287 (P), accumulate
  gemm32<1,1>(o0, o1, HL, 136, P.wt + OFF_BD + wave*16*288, 288, 256, n0, q);
  __syncthreads();   // BD3 HL reads done before R2 (aliases HL) is written

  // l2 epilogue: wave0 tile -> j=n0 (0..15), wave1 tile -> j=16+n0 (n0<3)
  #pragma unroll
  for (int s = 0; s < 2; ++s) {
    const f32x4* O_ = s ? o1 : o0;
    #pragma unroll
    for (int r = 0; r < 4; ++r) {
      const int p = s*16 + q*4 + r;
      if (wave == 0) {
        float v0 = O_[0][r] + rc;
        if (n0 < 6) v0 = tanhf(v0);
        R2[p*20 + n0] = v0;
      } else if (n0 < 3) {
        R2[p*20 + 16 + n0] = O_[0][r] + rc;
      }
    }
  }
  __syncthreads();

  // ---- final packing (TIME=0 -> cos(phases))
  if (tid < 32) {
    const int gp2 = p0 + tid;
    if (gp2 < P.N) {
      const float* r = R2 + tid*20;
      float* o = P.out + (size_t)gp2*13;
      o[0] = r[0]*cosf(r[6]);
      o[1] = r[1]*cosf(r[7]);
      o[2] = r[2]*cosf(r[8]);
      o[3] = r[3]*cosf(r[9]);
      o[4] = r[4]*cosf(r[10]);
      o[5] = r[5]*cosf(r[11]);
      o[6] = 1.f + sigmoid_(r[12])*10.f;
      o[7] = 1.f + sigmoid_(r[13])*2.f;
      o[8] = sigmoid_(r[14])*0.01f;
      o[9]  = r[15];
      o[10] = r[16];
      o[11] = r[17];
      o[12] = r[18];
    }
  }
}

// ================= fallback fused kernel (ws too small) =================
__global__ __launch_bounds__(256, 3)
void em_nerf_fallback(Params P)
{
  __shared__ __align__(16) char smem[44288];
  short* featB = (short*)smem;
  short* hA    = (short*)(smem + 9216);
  short* hB    = (short*)(smem + 9216 + 17664);
  float* headF = (float*)(smem + 9216);
  float* res2  = (float*)smem;
  __shared__ int s_res[16];

  const int tid = threadIdx.x;
  if (tid < 16) s_res[tid] = P.res[tid];
  __syncthreads();
  {
    const int p = tid & 63;
    const int g = tid >> 6;
    int gp = blockIdx.x*64 + p; if (gp >= P.N) gp = P.N - 1;
    const float xs0 = fminf(fmaxf(P.x[gp*3+0], 0.f), 1.f);
    const float xs1 = fminf(fmaxf(P.x[gp*3+1], 0.f), 1.f);
    const float xs2 = fminf(fmaxf(P.x[gp*3+2], 0.f), 1.f);
    #pragma unroll
    for (int j = 0; j < 4; ++j) {
      const int l = g*4 + j;
      const int res = s_res[l];
      const float rf = (float)(res-1);
      const float s0 = xs0*rf, s1 = xs1*rf, s2 = xs2*rf;
      int f0i = (int)s0; if (f0i > res-1) f0i = res-1;
      int f1i = (int)s1; if (f1i > res-1) f1i = res-1;
      int f2i = (int)s2; if (f2i > res-1) f2i = res-1;
      const float w0 = s0 - (float)f0i;
      const float w1 = s1 - (float)f1i;
      const float w2 = s2 - (float)f2i;
      int c0i = f0i+1; if (c0i > res-1) c0i = res-1;
      int c1i = f1i+1; if (c1i > res-1) c1i = res-1;
      int c2i = f2i+1; if (c2i > res-1) c2i = res-1;
      const int hx0 = (f0i*PM0) & TMASK, hx1 = (c0i*PM0) & TMASK;
      const int hy0 = (f1i*PM1) & TMASK, hy1 = (c1i*PM1) & TMASK;
      const int hz0 = (f2i*PM2) & TMASK, hz1 = (c2i*PM2) & TMASK;
      const float* tp = P.tables + ((size_t)l << 20);
      float a0 = 0.f, a1 = 0.f;
      #pragma unroll
      for (int cn = 0; cn < 8; ++cn) {
        const int bx = (cn>>2)&1, by = (cn>>1)&1, bz = cn&1;
        const int hh = ((bx?hx1:hx0) + (by?hy1:hy0) + (bz?hz1:hz0)) & TMASK;
        const float cw = (bx?w0:1.f-w0)*(by?w1:1.f-w1)*(bz?w2:1.f-w2);
        const float2 tv = *(const float2*)(tp + 2*hh);
        a0 = fmaf(cw, tv.x, a0);
        a1 = fmaf(cw, tv.y, a1);
      }
      featB[p*72 + 2*l]   = f2bf(a0);
      featB[p*72 + 2*l+1] = f2bf(a1);
    }
    if (g == 0) {
      float fr = P.freq[gp];
      fr = fminf(fmaxf(fr, 1e6f), 1e12f);
      const float nf = (log10f(fr) - 6.f) * (1.f/6.f);
      float a = 3.14159274101257324f * nf;
      #pragma unroll
      for (int i = 0; i < 10; ++i) {
        featB[p*72 + 32 + 2*i] = f2bf(sinf(a));
        featB[p*72 + 33 + 2*i] = f2bf(cosf(a));
        a = a * 2.f;
      }
    }
    if (g == 3) {
      #pragma unroll
      for (int k = 52; k < 64; ++k) featB[p*72 + k] = 0;
    }
  }
  __syncthreads();

  const int lane = tid & 63, wave = tid >> 6;
  const int n0 = lane & 15, q = lane >> 4;
  short* myA  = featB + wave*16*72;
  short* myH1 = hA + wave*16*136;
  short* myH2 = hB + wave*16*136;

  auto gemm1 = [&](const short* A, int lda, const short* wt, int kpad, int kwoff, int KC, f32x4* acc, int NT){
    const short* Ap = A + n0*lda + q*8;
    const short* Bp = wt + n0*kpad + kwoff + q*8;
    for (int kc = 0; kc < KC; ++kc) {
      bf16x8 a = *(const bf16x8*)(Ap + kc*32);
      for (int nt = 0; nt < NT; ++nt) {
        bf16x8 b = *(const bf16x8*)(Bp + nt*16*kpad + kc*32);
        acc[nt] = __builtin_amdgcn_mfma_f32_16x16x32_bf16(a, b, acc[nt], 0, 0, 0);
      }
    }
  };
  auto epi1 = [&](const f32x4* acc, const float* bias, short* out, int ldo, int NT, bool relu){
    for (int nt = 0; nt < NT; ++nt) {
      const float bv = bias[nt*16 + n0];
      for (int r = 0; r < 4; ++r) {
        float v = acc[nt][r] + bv;
        if (relu) v = fmaxf(v, 0.f);
        out[(q*4 + r)*ldo + nt*16 + n0] = f2bf(v);
      }
    }
  };

  { f32x4 acc[8] = {}; gemm1(myA, 72, P.wt + OFF_W0, 64, 0, 2, acc, 8);  epi1(acc, P.b0, myH1, 136, 8, true); }
  __syncthreads();
  { f32x4 acc[8] = {}; gemm1(myH1, 136, P.wt + OFF_W1, 128, 0, 4, acc, 8); epi1(acc, P.b1, myH2, 136, 8, true); }
  __syncthreads();
  { f32x4 acc[8] = {}; gemm1(myH2, 136, P.wt + OFF_W2, 192, 0, 4, acc, 8);
    gemm1(myA, 72, P.wt + OFF_W2, 192, 128, 2, acc, 8); epi1(acc, P.b2, myH1, 136, 8, true); }
  __syncthreads();
  { f32x4 acc[8] = {}; gemm1(myH1, 136, P.wt + OFF_W3, 128, 0, 4, acc, 8); epi1(acc, P.b3, myH2, 136, 8, true); }
  __syncthreads();

  float* hf = headF + wave*16*69;
  auto head1f = [&](const short* wt, const float* bias, int NT, bool relu){
    f32x4 acc[4] = {};
    gemm1(myH2, 136, wt, 128, 0, 4, acc, NT);
    for (int nt = 0; nt < NT; ++nt) {
      const float bv = bias[nt*16 + n0];
      for (int r = 0; r < 4; ++r) {
        float v = acc[nt][r] + bv;
        if (relu) v = fmaxf(v, 0.f);
        hf[(q*4 + r)*69 + nt*16 + n0] = v;
      }
    }
  };
  auto l2 = [&](int OC2, int K2, bool ln, bool th, const float* g, const float* be,
                const float* W2, const float* b2, int slot){
    __syncthreads();
    if (tid < 64) {
      const float* row = headF + tid*69;
      float mn = 0.f, iv = 1.f;
      if (ln) {
        float s = 0.f;
        for (int k = 0; k < K2; ++k) s += row[k];
        mn = s/(float)K2;
        float vv = 0.f;
        for (int k = 0; k < K2; ++k) { float d = row[k]-mn; vv = fmaf(d,d,vv); }
        iv = 1.f/sqrtf(vv/(float)K2 + 1e-5f);
      }
      for (int j = 0; j < OC2; ++j) {
        float acc = b2[j];
        for (int k = 0; k < K2; ++k) {
          float xv = row[k];
          if (ln) xv = (xv-mn)*iv*g[k] + be[k];
          xv = fmaxf(xv, 0.f);
          acc = fmaf(xv, W2[k*OC2+j], acc);
        }
        res2[tid*20 + slot + j] = th ? tanhf(acc) : acc;
      }
    }
    __syncthreads();
  };

  head1f(P.wt + OFF_E, P.e_b1, 4, false); l2(3, 64, true,  true,  P.e_g, P.e_be, P.e_w2, P.e_b2, 0);
  head1f(P.wt + OFF_E + 8192, P.m_b1, 4, false); l2(3, 64, true, true, P.m_g, P.m_be, P.m_w2, P.m_b2, 3);
  head1f(P.wt + OFF_P, P.p_b1, 2, true);  l2(6, 32, false, false, 0, 0, P.p_w2, P.p_b2, 6);
  head1f(P.wt + OFF_MAT, P.mat_b1, 4, true); l2(3, 64, false, false, 0, 0, P.mat_w2, P.mat_b2, 12);
  head1f(P.wt + OFF_S, P.s_b1, 4, true);  l2(4, 64, false, false, 0, 0, P.s_w2, P.s_b2, 15);

  if (tid < 64) {
    const int gp = blockIdx.x*64 + tid;
    if (gp < P.N) {
      const float* r = res2 + tid*20;
      float* o = P.out + (size_t)gp*13;
      o[0] = r[0]*cosf(r[6]);
      o[1] = r[1]*cosf(r[7]);
      o[2] = r[2]*cosf(r[8]);
      o[3] = r[3]*cosf(r[9]);
      o[4] = r[4]*cosf(r[10]);
      o[5] = r[5]*cosf(r[11]);
      o[6] = 1.f + sigmoid_(r[12])*10.f;
      o[7] = 1.f + sigmoid_(r[13])*2.f;
      o[8] = sigmoid_(r[14])*0.01f;
      o[9]  = r[15];
      o[10] = r[16];
      o[11] = r[17];
      o[12] = r[18];
    }
  }
}

extern "C" void kernel_launch(void* const* d_in, const int* in_sizes, int n_in,
                              void* d_out, int out_size, void* d_ws, size_t ws_size,
                              hipStream_t stream) {
  (void)n_in; (void)out_size;
  const float** in = (const float**)d_in;
  const int N = in_sizes[0] / 3;

  PrepParams PP;
  const float* srcs[9] = { in[3], in[5], in[7], in[9], in[11], in[15], in[19], in[23], in[27] };
  const int ends[9]  = { 8192, 24576, 49152, 65536, 73728, 81920, 86016, 94208, 102400 };
  const int nsrc[9]  = { 128, 128, 128, 128, 64, 64, 32, 64, 64 };
  const int ksrc[9]  = { 52, 128, 180, 128, 128, 128, 128, 128, 128 };
  const int kpad[9]  = { 64, 128, 192, 128, 128, 128, 128, 128, 128 };
  for (int i = 0; i < 9; ++i) { PP.src[i]=srcs[i]; PP.end[i]=ends[i]; PP.Nsrc[i]=nsrc[i]; PP.Ksrc[i]=ksrc[i]; PP.Kpad[i]=kpad[i]; }
  PP.wt = (short*)d_ws;
  hipLaunchKernelGGL(prep_weights, dim3((WT_TOTAL+255)/256), dim3(256), 0, stream, PP);

  BdParams BP;
  BP.e = in[13]; BP.m = in[17]; BP.p = in[21]; BP.mat = in[25]; BP.s = in[29];
  BP.out = (short*)d_ws + OFF_BD;
  hipLaunchKernelGGL(prep_bd, dim3((32*288 + 255)/256), dim3(256), 0, stream, BP);

  Params P;
  P.x = in[0]; P.freq = in[1]; P.tables = in[2];
  P.b0 = in[4]; P.b1 = in[6]; P.b2 = in[8]; P.b3 = in[10];
  P.e_b1 = in[12]; P.e_w2 = in[13]; P.e_b2 = in[14];
  P.m_b1 = in[16]; P.m_w2 = in[17]; P.m_b2 = in[18];
  P.p_b1 = in[20]; P.p_w2 = in[21]; P.p_b2 = in[22];
  P.mat_b1 = in[24]; P.mat_w2 = in[25]; P.mat_b2 = in[26];
  P.s_b1 = in[28]; P.s_w2 = in[29]; P.s_b2 = in[30];
  P.e_g = in[31]; P.e_be = in[32]; P.m_g = in[33]; P.m_be = in[34];
  P.wt = (const short*)d_ws;
  P.feat = (const unsigned*)((const char*)d_ws + WS_FEAT_OFF);
  P.out = (float*)d_out;
  P.N = N;

  const double B = exp((log(512.0) - log(16.0)) / 15.0);
  for (int l = 0; l < 16; ++l) {
    double r = 16.0 * pow(B, (double)l);
    int ri = (int)r;
    if (ri > 512) ri = 512;
    P.res[l] = ri;
  }

  const size_t feat_bytes = (size_t)N*8*4;
  const size_t need = (size_t)WS_FEAT_OFF + feat_bytes + DENSE_BYTES;

  if (ws_size >= need) {
    char* dense_base = (char*)d_ws + WS_FEAT_OFF + feat_bytes;
    P.dense = (const unsigned short*)dense_base;

    TabPrepParams TP;
    TP.tables = in[2];
    TP.tab8 = (unsigned*)((char*)d_ws + WS_TAB8_OFF);
    hipLaunchKernelGGL(tab_prep, dim3((16*524288/2 + 255)/256), dim3(256), 0, stream, TP);

    DensePrepParams DP;
    DP.tab8 = (const unsigned short*)((const char*)d_ws + WS_TAB8_OFF);
    DP.dense = (unsigned short*)dense_base;
    hipLaunchKernelGGL(dense_prep8, dim3((DENSE_USHORTS + 255)/256), dim3(256), 0, stream, DP);

    HashParams HP;
    HP.x = in[0];
    HP.tab8 = (const unsigned short*)((const char*)d_ws + WS_TAB8_OFF);
    HP.feat = (unsigned*)((char*)d_ws + WS_FEAT_OFF);
    HP.N = N;
    for (int l = 0; l < 16; ++l) HP.res[l] = P.res[l];
    const int strips = (N + 511) / 512;
    hipLaunchKernelGGL(hash_encode8u, dim3(strips*8), dim3(256), 0, stream, HP);

    hipLaunchKernelGGL(em_nerf6, dim3((N + 31) / 32), dim3(128), 0, stream, P);
  } else {
    P.dense = nullptr;
    hipLaunchKernelGGL(em_nerf_fallback, dim3((N + 63) / 64), dim3(256), 0, stream, P);
  }
}